// Round 8
// baseline (227.537 us; speedup 1.0000x reference)
//
#include <hip/hip_runtime.h>
#include <hip/hip_bf16.h>
#include <stdint.h>

// Problem: B=2, S=4096, D=512, H=8, hd=64. fp32 in/out, bf16 MFMA internally.
// Dispatches: cvt_all -> gemm_qkv -> flash -> gemm_out.
//
// ws layout:
//   [0,   8MB)  Xb    bf16 [8192,512]
//   [8,  10MB)  Wqt/Wkt/Wvt/Wot bf16 [512,512] each ([n][k]; QKV contiguous)
//   [10, 18MB)  Qb    bf16 [B,H,S,64]  (pre-scaled by 0.125*log2e)
//   [18, 26MB)  Kb    bf16 [B,H,S,64]
//   [26, 34MB)  Vtb   bf16 [B,H,64,S]
//   [34, 42MB)  Atb   bf16 [B,S,512]

typedef __bf16 bf16x8 __attribute__((ext_vector_type(8)));
typedef float f32x4 __attribute__((ext_vector_type(4)));

using as1_void = __attribute__((address_space(1))) void;
using as3_void = __attribute__((address_space(3))) void;

__device__ __forceinline__ void gload16(const void* g, void* l) {
    __builtin_amdgcn_global_load_lds((const as1_void*)g, (as3_void*)l, 16, 0, 0);
}

__device__ __forceinline__ f32x4 mfma16(bf16x8 a, bf16x8 b, f32x4 c) {
    return __builtin_amdgcn_mfma_f32_16x16x32_bf16(a, b, c, 0, 0, 0);
}

// pack two fp32 -> bf16 pair (round-half-up) in 3 VALU ops: low16 = bf(a).
__device__ __forceinline__ uint32_t pk2(float a, float b) {
    uint32_t ua = __builtin_bit_cast(uint32_t, a) + 0x8000u;
    uint32_t ub = __builtin_bit_cast(uint32_t, b) + 0x8000u;
    return __builtin_amdgcn_perm(ub, ua, 0x07060302u);
}

// ---------------------------------------------------------------- converts (fused)
__global__ void cvt_all(const float* __restrict__ X, __hip_bfloat16* __restrict__ Xb,
                        const float* __restrict__ w0, const float* __restrict__ w1,
                        const float* __restrict__ w2, const float* __restrict__ w3,
                        __hip_bfloat16* __restrict__ o0, __hip_bfloat16* __restrict__ o1,
                        __hip_bfloat16* __restrict__ o2, __hip_bfloat16* __restrict__ o3) {
    __shared__ float t[32][33];
    const int bid = blockIdx.x, tid = threadIdx.x;
    if (bid < 1024) {
        const float* W; __hip_bfloat16* O;
        switch (bid >> 8) {
            case 0: W = w0; O = o0; break;
            case 1: W = w1; O = o1; break;
            case 2: W = w2; O = o2; break;
            default: W = w3; O = o3; break;
        }
        int rem = bid & 255;
        int n0 = (rem & 15) * 32, k0 = (rem >> 4) * 32;
        int tx = tid & 31, ty = tid >> 5;
        for (int j = 0; j < 4; ++j)
            t[ty + 8 * j][tx] = W[(size_t)(k0 + ty + 8 * j) * 512 + n0 + tx];
        __syncthreads();
        for (int j = 0; j < 4; ++j)
            O[(size_t)(n0 + ty + 8 * j) * 512 + k0 + tx] = __float2bfloat16(t[tx][ty + 8 * j]);
    } else {
        int i = ((bid - 1024) * 256 + tid) * 4;
        float4 v = *reinterpret_cast<const float4*>(X + i);
        uint2 u;
        u.x = pk2(v.x, v.y);
        u.y = pk2(v.z, v.w);
        *reinterpret_cast<uint2*>(Xb + i) = u;
    }
}

// ---------------------------------------------------------------- fused QKV GEMM
// Bt = [Wqt;Wkt;Wvt] bf16 [1536][512]. seg = tileN>>9 (block-uniform).
// seg<2 (Q/K): swapped operands -> C^T: lane rows = d (consecutive) -> 8B stores.
// seg==2 (V): normal orientation -> lane rows = s (consecutive) -> 8B stores.
__global__ __launch_bounds__(256, 2) void gemm_qkv(
    const __hip_bfloat16* __restrict__ A, const __hip_bfloat16* __restrict__ Bt,
    const float* __restrict__ bq, const float* __restrict__ bk, const float* __restrict__ bv,
    __hip_bfloat16* __restrict__ Qb, __hip_bfloat16* __restrict__ Kb,
    __hip_bfloat16* __restrict__ Vtb, float qs)
{
    const int K = 512;
    __shared__ __hip_bfloat16 Abuf[128 * 32];
    __shared__ __hip_bfloat16 Bbuf[128 * 32];
    const int tid = threadIdx.x, w = tid >> 6, lane = tid & 63;
    const int col = lane & 15, quad = lane >> 4;
    const int wr = w >> 1, wc = w & 1;
    const int tileN = blockIdx.x * 128, tileM = blockIdx.y * 128;
    const int seg = tileN >> 9;

    f32x4 acc[4][4] = {};

    for (int k0 = 0; k0 < K; k0 += 32) {
        for (int i = 0; i < 2; ++i) {
            int g = w * 2 + i;
            int chunk = g * 64 + lane;
            int row = chunk >> 2, c8 = chunk & 3;
            gload16(A + (size_t)(tileM + row) * K + k0 + c8 * 8, Abuf + g * 512);
            gload16(Bt + (size_t)(tileN + row) * K + k0 + c8 * 8, Bbuf + g * 512);
        }
        __syncthreads();
        bf16x8 af[4], bfr[4];
        for (int mt = 0; mt < 4; ++mt)
            af[mt] = *reinterpret_cast<const bf16x8*>(Abuf + (wr * 64 + mt * 16 + col) * 32 + quad * 8);
        for (int nt = 0; nt < 4; ++nt)
            bfr[nt] = *reinterpret_cast<const bf16x8*>(Bbuf + (wc * 64 + nt * 16 + col) * 32 + quad * 8);
        if (seg < 2) {
            for (int mt = 0; mt < 4; ++mt)
                for (int nt = 0; nt < 4; ++nt)
                    acc[nt][mt] = mfma16(bfr[nt], af[mt], acc[nt][mt]);   // C^T
        } else {
            for (int mt = 0; mt < 4; ++mt)
                for (int nt = 0; nt < 4; ++nt)
                    acc[mt][nt] = mfma16(af[mt], bfr[nt], acc[mt][nt]);
        }
        __syncthreads();
    }

    const int nbase = (tileN & 511) + wc * 64;
    if (seg < 2) {
        const float* bias = (seg == 0) ? bq : bk;
        const float scale = (seg == 0) ? qs : 1.0f;
        __hip_bfloat16* outp = (seg == 0) ? Qb : Kb;
        for (int nt = 0; nt < 4; ++nt) {
            int nn0 = nbase + nt * 16 + quad * 4;
            f32x4 b4 = *reinterpret_cast<const f32x4*>(bias + nn0);
            int h = nn0 >> 6, d0 = nn0 & 63;
            for (int mt = 0; mt < 4; ++mt) {
                int m = tileM + wr * 64 + mt * 16 + col;
                int b = m >> 12, s = m & 4095;
                f32x4 v = (acc[nt][mt] + b4) * scale;
                uint2 u;
                u.x = pk2(v[0], v[1]);
                u.y = pk2(v[2], v[3]);
                *reinterpret_cast<uint2*>(outp + (((size_t)(b * 8 + h) * 4096 + s) << 6) + d0) = u;
            }
        }
    } else {
        for (int nt = 0; nt < 4; ++nt) {
            int nn0 = nbase + nt * 16 + col;
            int h = nn0 >> 6, d = nn0 & 63;
            float bn = bv[nn0];
            for (int mt = 0; mt < 4; ++mt) {
                int s0 = tileM + wr * 64 + mt * 16 + quad * 4;
                int b = s0 >> 12;
                f32x4 v = acc[mt][nt];
                uint2 u;
                u.x = pk2(v[0] + bn, v[1] + bn);
                u.y = pk2(v[2] + bn, v[3] + bn);
                *reinterpret_cast<uint2*>(Vtb + (((size_t)(b * 8 + h) * 64 + d) << 12) + (s0 & 4095)) = u;
            }
        }
    }
}

// ---------------------------------------------------------------- final GEMM (Wo)
// Swapped operands -> lane rows = n consecutive -> float4 16B stores.
__global__ __launch_bounds__(256, 2) void gemm_out(
    const __hip_bfloat16* __restrict__ A, const __hip_bfloat16* __restrict__ Bt,
    const float* __restrict__ bias, float* __restrict__ out)
{
    const int K = 512;
    __shared__ __hip_bfloat16 Abuf[128 * 32];
    __shared__ __hip_bfloat16 Bbuf[64 * 32];
    const int tid = threadIdx.x, w = tid >> 6, lane = tid & 63;
    const int col = lane & 15, quad = lane >> 4;
    const int tileN = blockIdx.x * 64, tileM = blockIdx.y * 128;

    f32x4 acc[4][2] = {};

    for (int k0 = 0; k0 < K; k0 += 32) {
        for (int i = 0; i < 2; ++i) {
            int g = w * 2 + i;
            int chunk = g * 64 + lane;
            int row = chunk >> 2, c8 = chunk & 3;
            gload16(A + (size_t)(tileM + row) * K + k0 + c8 * 8, Abuf + g * 512);
        }
        {
            int row = tid >> 2, c8 = tid & 3;
            gload16(Bt + (size_t)(tileN + row) * K + k0 + c8 * 8, Bbuf + tid * 8);
        }
        __syncthreads();
        bf16x8 af[2], bfr[4];
        for (int mt = 0; mt < 2; ++mt)
            af[mt] = *reinterpret_cast<const bf16x8*>(Abuf + (w * 32 + mt * 16 + col) * 32 + quad * 8);
        for (int nt = 0; nt < 4; ++nt)
            bfr[nt] = *reinterpret_cast<const bf16x8*>(Bbuf + (nt * 16 + col) * 32 + quad * 8);
        for (int mt = 0; mt < 2; ++mt)
            for (int nt = 0; nt < 4; ++nt)
                acc[nt][mt] = mfma16(bfr[nt], af[mt], acc[nt][mt]);   // C^T
        __syncthreads();
    }

    for (int nt = 0; nt < 4; ++nt) {
        int n0 = tileN + nt * 16 + quad * 4;
        f32x4 b4 = *reinterpret_cast<const f32x4*>(bias + n0);
        for (int mt = 0; mt < 2; ++mt) {
            int m = tileM + w * 32 + mt * 16 + col;
            f32x4 v = acc[nt][mt] + b4;
            *reinterpret_cast<f32x4*>(out + (size_t)m * 512 + n0) = v;
        }
    }
}

// ---------------------------------------------------------------- flash attention (v5)
// v4 pipelined structure + (1) pk2 3-op bf16 pair pack, (2) hoisted
// loop-invariant LDS addresses (swizzles -> VGPR bases + imm offsets),
// (3) z4-seeded first QK MFMA (no sc zero-init movs).
__global__ __launch_bounds__(256) void flash(
    const __hip_bfloat16* __restrict__ Q,   // [B*H, 4096, 64] (pre-scaled)
    const __hip_bfloat16* __restrict__ Kq,  // [B*H, 4096, 64]
    const __hip_bfloat16* __restrict__ Vt,  // [B*H, 64, 4096]
    __hip_bfloat16* __restrict__ attnb)     // [B, 4096, 512]
{
    __shared__ __hip_bfloat16 KT[2][4096];  // 16 KB
    __shared__ __hip_bfloat16 VB[2][4096];  // 16 KB
    __shared__ uint32_t TB[4][1024];        // 16 KB, per-wave P^T staging

    const int bh = blockIdx.y, b = bh >> 3, h = bh & 7;
    const int tid = threadIdx.x, w = tid >> 6, lane = tid & 63;
    const int col = lane & 15, quad = lane >> 4;
    const int q0 = blockIdx.x * 128 + w * 32;
    const int c7 = col & 7;

    const __hip_bfloat16* Qh = Q + (size_t)bh * 4096 * 64;
    const __hip_bfloat16* Kh = Kq + (size_t)bh * 4096 * 64;
    const __hip_bfloat16* Vh = Vt + (size_t)bh * 64 * 4096;

    bf16x8 aq[2][2];
    for (int qh = 0; qh < 2; ++qh)
        for (int ks = 0; ks < 2; ++ks)
            aq[qh][ks] = *reinterpret_cast<const bf16x8*>(
                Qh + (size_t)(q0 + qh * 16 + col) * 64 + ks * 32 + quad * 8);

    const __hip_bfloat16* ksrc[2];
    const __hip_bfloat16* vsrc[2];
    int ldsoff[2];
    for (int i = 0; i < 2; ++i) {
        int c = i * 256 + tid;
        int row = c >> 3, s8 = (c & 7) ^ (row & 7);
        ksrc[i] = Kh + row * 64 + s8 * 8;
        vsrc[i] = Vh + (size_t)row * 4096 + s8 * 8;
        ldsoff[i] = (i * 256 + w * 64) * 8;
    }

    bf16x8 ones;
    for (int j = 0; j < 8; ++j) ones[j] = (__bf16)1.0f;

    f32x4 o[4][2] = {};
    f32x4 accl[2] = {};
    f32x4 sc[2][4][2];
    const f32x4 z4 = {0.f, 0.f, 0.f, 0.f};

    // hoisted loop-invariant LDS byte-address bases
    const char* KTb = (const char*)&KT[0][0];
    const char* VBb = (const char*)&VB[0][0];
    char* TBb = (char*)&TB[w][0];
    const int ra0 = col * 128 + ((quad ^ c7) * 16);          // ks=0 read swizzle
    const int ra1 = col * 128 + (((4 + quad) ^ c7) * 16);    // ks=1 read swizzle
    int two[4];                                              // TB write addrs (kg)
    {
        int basew = col * 128 + (((quad >> 1) ^ (c7 & 1)) * 16) + ((quad & 1) * 8);
        for (int j = 0; j < 4; ++j) two[j] = basew + ((j ^ (c7 >> 1)) * 32);
    }

    // prologue: stage K0,V0,K1; QK(0) -> sc[0]
    gload16(ksrc[0], &KT[0][ldsoff[0]]);
    gload16(ksrc[1], &KT[0][ldsoff[1]]);
    gload16(vsrc[0], &VB[0][ldsoff[0]]);
    gload16(vsrc[1], &VB[0][ldsoff[1]]);
    gload16(ksrc[0] + 4096, &KT[1][ldsoff[0]]);
    gload16(ksrc[1] + 4096, &KT[1][ldsoff[1]]);
    __syncthreads();

    for (int kg = 0; kg < 4; ++kg) {
        bf16x8 ak = *reinterpret_cast<const bf16x8*>(KTb + kg * 2048 + ra0);
        for (int qh = 0; qh < 2; ++qh)
            sc[0][kg][qh] = mfma16(ak, aq[qh][0], z4);
    }
    for (int kg = 0; kg < 4; ++kg) {
        bf16x8 ak = *reinterpret_cast<const bf16x8*>(KTb + kg * 2048 + ra1);
        for (int qh = 0; qh < 2; ++qh)
            sc[0][kg][qh] = mfma16(ak, aq[qh][1], sc[0][kg][qh]);
    }
    __syncthreads();   // KT[0] reads done before body(0) overwrites it

#define FLASH_BODY(KT_, P_)                                                      \
    {                                                                            \
        const int kt_ = (KT_);                                                   \
        int kk = kt_ + 2; if (kk > 63) kk = 63;                                  \
        gload16(ksrc[0] + (size_t)kk * 4096, &KT[(P_)][ldsoff[0]]);              \
        gload16(ksrc[1] + (size_t)kk * 4096, &KT[(P_)][ldsoff[1]]);              \
        gload16(vsrc[0] + (size_t)(kt_ + 1) * 64, &VB[1 - (P_)][ldsoff[0]]);     \
        gload16(vsrc[1] + (size_t)(kt_ + 1) * 64, &VB[1 - (P_)][ldsoff[1]]);     \
        /* softmax(kt): p = exp2(s), pack (pk2), store P^T */                    \
        for (int kg = 0; kg < 4; ++kg)                                           \
            for (int qh = 0; qh < 2; ++qh) {                                     \
                f32x4 v = sc[(P_)][kg][qh];                                      \
                uint2 u;                                                         \
                u.x = pk2(__builtin_amdgcn_exp2f(v[0]),                          \
                          __builtin_amdgcn_exp2f(v[1]));                         \
                u.y = pk2(__builtin_amdgcn_exp2f(v[2]),                          \
                          __builtin_amdgcn_exp2f(v[3]));                         \
                *reinterpret_cast<uint2*>(TBb + qh * 2048 + two[kg]) = u;        \
            }                                                                    \
        /* QK(kt+1) -> sc[1-P], z4-seeded */                                     \
        for (int kg = 0; kg < 4; ++kg) {                                         \
            bf16x8 ak = *reinterpret_cast<const bf16x8*>(                        \
                KTb + (1 - (P_)) * 8192 + kg * 2048 + ra0);                      \
            for (int qh = 0; qh < 2; ++qh)                                       \
                sc[1 - (P_)][kg][qh] = mfma16(ak, aq[qh][0], z4);                \
        }                                                                        \
        for (int kg = 0; kg < 4; ++kg) {                                         \
            bf16x8 ak = *reinterpret_cast<const bf16x8*>(                        \
                KTb + (1 - (P_)) * 8192 + kg * 2048 + ra1);                      \
            for (int qh = 0; qh < 2; ++qh)                                       \
                sc[1 - (P_)][kg][qh] = mfma16(ak, aq[qh][1], sc[1 - (P_)][kg][qh]); \
        }                                                                        \
        /* PV(kt) */                                                             \
        bf16x8 bp[2][2];                                                         \
        for (int qh = 0; qh < 2; ++qh) {                                         \
            bp[qh][0] = *reinterpret_cast<const bf16x8*>(TBb + qh * 2048 + ra0); \
            bp[qh][1] = *reinterpret_cast<const bf16x8*>(TBb + qh * 2048 + ra1); \
        }                                                                        \
        for (int ks = 0; ks < 2; ++ks) {                                         \
            for (int dt = 0; dt < 4; ++dt) {                                     \
                bf16x8 av = *reinterpret_cast<const bf16x8*>(                    \
                    VBb + (P_) * 8192 + dt * 2048 + (ks ? ra1 : ra0));           \
                for (int qh = 0; qh < 2; ++qh)                                   \
                    o[dt][qh] = mfma16(av, bp[qh][ks], o[dt][qh]);               \
            }                                                                    \
            accl[0] = mfma16(ones, bp[0][ks], accl[0]);                          \
            accl[1] = mfma16(ones, bp[1][ks], accl[1]);                          \
        }                                                                        \
        __syncthreads();                                                         \
    }

    FLASH_BODY(0, 0)
    for (int kth = 0; kth < 31; ++kth) {
        FLASH_BODY(2 * kth + 1, 1)
        FLASH_BODY(2 * kth + 2, 0)
    }
    // tail: tile 63 (parity 1), no staging, no barrier
    {
        for (int kg = 0; kg < 4; ++kg)
            for (int qh = 0; qh < 2; ++qh) {
                f32x4 v = sc[1][kg][qh];
                uint2 u;
                u.x = pk2(__builtin_amdgcn_exp2f(v[0]), __builtin_amdgcn_exp2f(v[1]));
                u.y = pk2(__builtin_amdgcn_exp2f(v[2]), __builtin_amdgcn_exp2f(v[3]));
                *reinterpret_cast<uint2*>(TBb + qh * 2048 + two[kg]) = u;
            }
        bf16x8 bp[2][2];
        for (int qh = 0; qh < 2; ++qh) {
            bp[qh][0] = *reinterpret_cast<const bf16x8*>(TBb + qh * 2048 + ra0);
            bp[qh][1] = *reinterpret_cast<const bf16x8*>(TBb + qh * 2048 + ra1);
        }
        for (int ks = 0; ks < 2; ++ks) {
            for (int dt = 0; dt < 4; ++dt) {
                bf16x8 av = *reinterpret_cast<const bf16x8*>(
                    VBb + 8192 + dt * 2048 + (ks ? ra1 : ra0));
                for (int qh = 0; qh < 2; ++qh)
                    o[dt][qh] = mfma16(av, bp[qh][ks], o[dt][qh]);
            }
            accl[0] = mfma16(ones, bp[0][ks], accl[0]);
            accl[1] = mfma16(ones, bp[1][ks], accl[1]);
        }
    }
#undef FLASH_BODY

    for (int qh = 0; qh < 2; ++qh) {
        float inv = 1.0f / accl[qh][0];
        int s = q0 + qh * 16 + col;
        __hip_bfloat16* dst = attnb + ((size_t)b * 4096 + s) * 512 + h * 64 + quad * 4;
        for (int dt = 0; dt < 4; ++dt) {
            uint2 u;
            u.x = pk2(o[dt][qh][0] * inv, o[dt][qh][1] * inv);
            u.y = pk2(o[dt][qh][2] * inv, o[dt][qh][3] * inv);
            *reinterpret_cast<uint2*>(dst + dt * 16) = u;
        }
    }
}

// ---------------------------------------------------------------- launch
extern "C" void kernel_launch(void* const* d_in, const int* in_sizes, int n_in,
                              void* d_out, int out_size, void* d_ws, size_t ws_size,
                              hipStream_t stream) {
    const float* X  = (const float*)d_in[0];
    const float* Wq = (const float*)d_in[1];
    const float* bq = (const float*)d_in[2];
    const float* Wk = (const float*)d_in[3];
    const float* bk = (const float*)d_in[4];
    const float* Wv = (const float*)d_in[5];
    const float* bv = (const float*)d_in[6];
    const float* Wo = (const float*)d_in[7];
    const float* bo = (const float*)d_in[8];
    float* out = (float*)d_out;

    char* ws = (char*)d_ws;
    __hip_bfloat16* Xb  = (__hip_bfloat16*)(ws);
    __hip_bfloat16* Wqt = (__hip_bfloat16*)(ws + ((size_t)8 << 20));
    __hip_bfloat16* Wkt = Wqt + 512 * 512;
    __hip_bfloat16* Wvt = Wkt + 512 * 512;
    __hip_bfloat16* Wot = Wvt + 512 * 512;
    __hip_bfloat16* Qb  = (__hip_bfloat16*)(ws + ((size_t)10 << 20));
    __hip_bfloat16* Kb  = (__hip_bfloat16*)(ws + ((size_t)18 << 20));
    __hip_bfloat16* Vtb = (__hip_bfloat16*)(ws + ((size_t)26 << 20));
    __hip_bfloat16* Atb = (__hip_bfloat16*)(ws + ((size_t)34 << 20));

    cvt_all<<<5120, 256, 0, stream>>>(X, Xb, Wq, Wk, Wv, Wo, Wqt, Wkt, Wvt, Wot);

    const float qs = 0.125f * 1.4426950408889634f;  // (1/sqrt(64)) * log2(e)
    gemm_qkv<<<dim3(12, 64), 256, 0, stream>>>(Xb, Wqt, bq, bk, bv, Qb, Kb, Vtb, qs);
    flash<<<dim3(32, 16), 256, 0, stream>>>(Qb, Kb, Vtb, Atb);
    gemm_out<<<dim3(8, 64), 256, 0, stream>>>(Atb, Wot, bo, out);
}

// Round 9
// 214.613 us; speedup vs baseline: 1.0602x; 1.0602x over previous
//
#include <hip/hip_runtime.h>
#include <hip/hip_bf16.h>
#include <stdint.h>

// Problem: B=2, S=4096, D=512, H=8, hd=64. fp32 in/out, bf16 MFMA internally.
// Dispatches: cvt_all -> gemm_qkv -> flash -> gemm_out.
// This round = R6's non-flash kernels (best residual 107.5us) + R7's flash
// (v4 pipelined, best flash 104.0us). No new mechanisms.
//
// ws layout:
//   [0,   8MB)  Xb    bf16 [8192,512]
//   [8,  10MB)  Wqt/Wkt/Wvt/Wot bf16 [512,512] each ([n][k]; QKV contiguous)
//   [10, 18MB)  Qb    bf16 [B,H,S,64]  (pre-scaled by 0.125*log2e)
//   [18, 26MB)  Kb    bf16 [B,H,S,64]
//   [26, 34MB)  Vtb   bf16 [B,H,64,S]
//   [34, 42MB)  Atb   bf16 [B,S,512]

typedef __bf16 bf16x8 __attribute__((ext_vector_type(8)));
typedef float f32x4 __attribute__((ext_vector_type(4)));

using as1_void = __attribute__((address_space(1))) void;
using as3_void = __attribute__((address_space(3))) void;

__device__ __forceinline__ void gload16(const void* g, void* l) {
    __builtin_amdgcn_global_load_lds((const as1_void*)g, (as3_void*)l, 16, 0, 0);
}

__device__ __forceinline__ f32x4 mfma16(bf16x8 a, bf16x8 b, f32x4 c) {
    return __builtin_amdgcn_mfma_f32_16x16x32_bf16(a, b, c, 0, 0, 0);
}

__device__ __forceinline__ uint32_t pkbf(float a, float b) {
    union { __hip_bfloat16 h[2]; uint32_t u; } r;
    r.h[0] = __float2bfloat16(a);   // low 16 = even element
    r.h[1] = __float2bfloat16(b);
    return r.u;
}

// ---------------------------------------------------------------- converts (fused)
// blocks [0,1024): weight transposes (256 blocks per weight, 32x32 tiles)
// blocks [1024,5120): X fp32 -> bf16 cast (4 elems/thread)
__global__ void cvt_all(const float* __restrict__ X, __hip_bfloat16* __restrict__ Xb,
                        const float* __restrict__ w0, const float* __restrict__ w1,
                        const float* __restrict__ w2, const float* __restrict__ w3,
                        __hip_bfloat16* __restrict__ o0, __hip_bfloat16* __restrict__ o1,
                        __hip_bfloat16* __restrict__ o2, __hip_bfloat16* __restrict__ o3) {
    __shared__ float t[32][33];
    const int bid = blockIdx.x, tid = threadIdx.x;
    if (bid < 1024) {
        const float* W; __hip_bfloat16* O;
        switch (bid >> 8) {
            case 0: W = w0; O = o0; break;
            case 1: W = w1; O = o1; break;
            case 2: W = w2; O = o2; break;
            default: W = w3; O = o3; break;
        }
        int rem = bid & 255;
        int n0 = (rem & 15) * 32, k0 = (rem >> 4) * 32;
        int tx = tid & 31, ty = tid >> 5;
        for (int j = 0; j < 4; ++j)
            t[ty + 8 * j][tx] = W[(size_t)(k0 + ty + 8 * j) * 512 + n0 + tx];
        __syncthreads();
        for (int j = 0; j < 4; ++j)
            O[(size_t)(n0 + ty + 8 * j) * 512 + k0 + tx] = __float2bfloat16(t[tx][ty + 8 * j]);
    } else {
        int i = ((bid - 1024) * 256 + tid) * 4;   // covers exactly 8192*512
        float4 v = *reinterpret_cast<const float4*>(X + i);
        uint2 u;
        u.x = pkbf(v.x, v.y);
        u.y = pkbf(v.z, v.w);
        *reinterpret_cast<uint2*>(Xb + i) = u;
    }
}

// ---------------------------------------------------------------- fused QKV GEMM (R6)
__global__ __launch_bounds__(256, 2) void gemm_qkv(
    const __hip_bfloat16* __restrict__ A, const __hip_bfloat16* __restrict__ Bt,
    const float* __restrict__ bq, const float* __restrict__ bk, const float* __restrict__ bv,
    __hip_bfloat16* __restrict__ Qb, __hip_bfloat16* __restrict__ Kb,
    __hip_bfloat16* __restrict__ Vtb, float qs)
{
    const int K = 512;
    __shared__ __hip_bfloat16 Abuf[128 * 32];
    __shared__ __hip_bfloat16 Bbuf[128 * 32];
    const int tid = threadIdx.x, w = tid >> 6, lane = tid & 63;
    const int col = lane & 15, quad = lane >> 4;
    const int wr = w >> 1, wc = w & 1;
    const int tileN = blockIdx.x * 128, tileM = blockIdx.y * 128;

    f32x4 acc[4][4] = {};

    for (int k0 = 0; k0 < K; k0 += 32) {
        for (int i = 0; i < 2; ++i) {
            int g = w * 2 + i;
            int chunk = g * 64 + lane;
            int row = chunk >> 2, c8 = chunk & 3;
            gload16(A + (size_t)(tileM + row) * K + k0 + c8 * 8, Abuf + g * 512);
            gload16(Bt + (size_t)(tileN + row) * K + k0 + c8 * 8, Bbuf + g * 512);
        }
        __syncthreads();
        bf16x8 af[4], bfr[4];
        for (int mt = 0; mt < 4; ++mt)
            af[mt] = *reinterpret_cast<const bf16x8*>(Abuf + (wr * 64 + mt * 16 + col) * 32 + quad * 8);
        for (int nt = 0; nt < 4; ++nt)
            bfr[nt] = *reinterpret_cast<const bf16x8*>(Bbuf + (wc * 64 + nt * 16 + col) * 32 + quad * 8);
        for (int mt = 0; mt < 4; ++mt)
            for (int nt = 0; nt < 4; ++nt)
                acc[mt][nt] = mfma16(af[mt], bfr[nt], acc[mt][nt]);
        __syncthreads();
    }

    const int seg = (tileN + wc * 64) >> 9;   // wave-uniform
    const float* bias = (seg == 0) ? bq : (seg == 1) ? bk : bv;
    const float scale = (seg == 0) ? qs : 1.0f;
    __hip_bfloat16* outp = (seg == 0) ? Qb : (seg == 1) ? Kb : Vtb;

    for (int mt = 0; mt < 4; ++mt) {
        for (int nt = 0; nt < 4; ++nt) {
            int n = tileN + wc * 64 + nt * 16 + col;
            int nn = n & 511, h = nn >> 6, d = nn & 63;
            float bn = bias[nn];
            for (int r = 0; r < 4; ++r) {
                int m = tileM + wr * 64 + mt * 16 + quad * 4 + r;
                int b = m >> 12, s = m & 4095;
                float v = (acc[mt][nt][r] + bn) * scale;
                size_t off;
                if (seg < 2) off = (((size_t)(b * 8 + h) * 4096 + s) << 6) + d;
                else         off = (((size_t)(b * 8 + h) * 64 + d) << 12) + s;
                outp[off] = __float2bfloat16(v);
            }
        }
    }
}

// ---------------------------------------------------------------- final GEMM (Wo) (R6)
// 128(M) x 64(N) tiles -> 512 blocks = 2 blocks/CU.
__global__ __launch_bounds__(256, 2) void gemm_out(
    const __hip_bfloat16* __restrict__ A, const __hip_bfloat16* __restrict__ Bt,
    const float* __restrict__ bias, float* __restrict__ out)
{
    const int N = 512, K = 512;
    __shared__ __hip_bfloat16 Abuf[128 * 32];
    __shared__ __hip_bfloat16 Bbuf[64 * 32];
    const int tid = threadIdx.x, w = tid >> 6, lane = tid & 63;
    const int col = lane & 15, quad = lane >> 4;
    const int tileN = blockIdx.x * 64, tileM = blockIdx.y * 128;

    f32x4 acc[2][4] = {};

    for (int k0 = 0; k0 < K; k0 += 32) {
        for (int i = 0; i < 2; ++i) {
            int g = w * 2 + i;
            int chunk = g * 64 + lane;
            int row = chunk >> 2, c8 = chunk & 3;
            gload16(A + (size_t)(tileM + row) * K + k0 + c8 * 8, Abuf + g * 512);
        }
        {
            int row = tid >> 2, c8 = tid & 3;
            gload16(Bt + (size_t)(tileN + row) * K + k0 + c8 * 8, Bbuf + tid * 8);
        }
        __syncthreads();
        bf16x8 af[2], bfr[4];
        for (int mt = 0; mt < 2; ++mt)
            af[mt] = *reinterpret_cast<const bf16x8*>(Abuf + (w * 32 + mt * 16 + col) * 32 + quad * 8);
        for (int nt = 0; nt < 4; ++nt)
            bfr[nt] = *reinterpret_cast<const bf16x8*>(Bbuf + (nt * 16 + col) * 32 + quad * 8);
        for (int mt = 0; mt < 2; ++mt)
            for (int nt = 0; nt < 4; ++nt)
                acc[mt][nt] = mfma16(af[mt], bfr[nt], acc[mt][nt]);
        __syncthreads();
    }

    for (int mt = 0; mt < 2; ++mt) {
        for (int nt = 0; nt < 4; ++nt) {
            int n = tileN + nt * 16 + col;
            float bn = bias[n];
            for (int r = 0; r < 4; ++r) {
                int m = tileM + w * 32 + mt * 16 + quad * 4 + r;
                out[(size_t)m * N + n] = acc[mt][nt][r] + bn;
            }
        }
    }
}

// ---------------------------------------------------------------- flash attention (v4 — measured 104.0us, R7)
// Software-pipelined: iteration kt runs softmax(kt)+PV(kt) (VALU + TB LDS)
// interleaved with QK(kt+1) (MFMA + ds_read) in ONE basic block.
__global__ __launch_bounds__(256) void flash(
    const __hip_bfloat16* __restrict__ Q,   // [B*H, 4096, 64] (pre-scaled)
    const __hip_bfloat16* __restrict__ Kq,  // [B*H, 4096, 64]
    const __hip_bfloat16* __restrict__ Vt,  // [B*H, 64, 4096]
    __hip_bfloat16* __restrict__ attnb)     // [B, 4096, 512]
{
    __shared__ __hip_bfloat16 KT[2][4096];  // 16 KB
    __shared__ __hip_bfloat16 VB[2][4096];  // 16 KB
    __shared__ uint32_t TB[4][1024];        // 16 KB, per-wave P^T staging

    const int bh = blockIdx.y, b = bh >> 3, h = bh & 7;
    const int tid = threadIdx.x, w = tid >> 6, lane = tid & 63;
    const int col = lane & 15, quad = lane >> 4;
    const int q0 = blockIdx.x * 128 + w * 32;
    const int c7 = col & 7;

    const __hip_bfloat16* Qh = Q + (size_t)bh * 4096 * 64;
    const __hip_bfloat16* Kh = Kq + (size_t)bh * 4096 * 64;
    const __hip_bfloat16* Vh = Vt + (size_t)bh * 64 * 4096;

    bf16x8 aq[2][2];
    for (int qh = 0; qh < 2; ++qh)
        for (int ks = 0; ks < 2; ++ks)
            aq[qh][ks] = *reinterpret_cast<const bf16x8*>(
                Qh + (size_t)(q0 + qh * 16 + col) * 64 + ks * 32 + quad * 8);

    const __hip_bfloat16* ksrc[2];
    const __hip_bfloat16* vsrc[2];
    int ldsoff[2];
    for (int i = 0; i < 2; ++i) {
        int c = i * 256 + tid;
        int row = c >> 3, s8 = (c & 7) ^ (row & 7);
        ksrc[i] = Kh + row * 64 + s8 * 8;
        vsrc[i] = Vh + (size_t)row * 4096 + s8 * 8;
        ldsoff[i] = (i * 256 + w * 64) * 8;
    }

    bf16x8 ones;
    for (int j = 0; j < 8; ++j) ones[j] = (__bf16)1.0f;

    f32x4 o[4][2] = {};
    f32x4 accl[2] = {};
    f32x4 sc[2][4][2];

    uint32_t* TBw = &TB[w][0];
    uint2* TBw2 = reinterpret_cast<uint2*>(TBw);

    gload16(ksrc[0], &KT[0][ldsoff[0]]);
    gload16(ksrc[1], &KT[0][ldsoff[1]]);
    gload16(vsrc[0], &VB[0][ldsoff[0]]);
    gload16(vsrc[1], &VB[0][ldsoff[1]]);
    gload16(ksrc[0] + 4096, &KT[1][ldsoff[0]]);
    gload16(ksrc[1] + 4096, &KT[1][ldsoff[1]]);
    __syncthreads();

    for (int kg = 0; kg < 4; ++kg)
        for (int qh = 0; qh < 2; ++qh)
            sc[0][kg][qh] = (f32x4){0.f, 0.f, 0.f, 0.f};
    for (int ks = 0; ks < 2; ++ks)
        for (int kg = 0; kg < 4; ++kg) {
            bf16x8 ak = *reinterpret_cast<const bf16x8*>(
                &KT[0][(kg * 16 + col) * 64 + (((ks * 4 + quad) ^ c7) << 3)]);
            for (int qh = 0; qh < 2; ++qh)
                sc[0][kg][qh] = mfma16(ak, aq[qh][ks], sc[0][kg][qh]);
        }
    __syncthreads();

#define FLASH_BODY(KT_, P_)                                                     \
    {                                                                           \
        const int kt_ = (KT_);                                                  \
        int kk = kt_ + 2; if (kk > 63) kk = 63;                                 \
        gload16(ksrc[0] + (size_t)kk * 4096, &KT[(P_)][ldsoff[0]]);             \
        gload16(ksrc[1] + (size_t)kk * 4096, &KT[(P_)][ldsoff[1]]);             \
        gload16(vsrc[0] + (size_t)(kt_ + 1) * 64, &VB[1 - (P_)][ldsoff[0]]);    \
        gload16(vsrc[1] + (size_t)(kt_ + 1) * 64, &VB[1 - (P_)][ldsoff[1]]);    \
        for (int kg = 0; kg < 4; ++kg)                                          \
            for (int qh = 0; qh < 2; ++qh) {                                    \
                f32x4 v = sc[(P_)][kg][qh];                                     \
                uint2 u;                                                        \
                u.x = pkbf(__builtin_amdgcn_exp2f(v[0]),                        \
                           __builtin_amdgcn_exp2f(v[1]));                       \
                u.y = pkbf(__builtin_amdgcn_exp2f(v[2]),                        \
                           __builtin_amdgcn_exp2f(v[3]));                       \
                TBw2[(qh * 16 + col) * 16 +                                     \
                     (((kg * 2 + (quad >> 1)) ^ c7) << 1) + (quad & 1)] = u;    \
            }                                                                   \
        for (int kg = 0; kg < 4; ++kg)                                          \
            for (int qh = 0; qh < 2; ++qh)                                      \
                sc[1 - (P_)][kg][qh] = (f32x4){0.f, 0.f, 0.f, 0.f};             \
        for (int ks = 0; ks < 2; ++ks)                                          \
            for (int kg = 0; kg < 4; ++kg) {                                    \
                bf16x8 ak = *reinterpret_cast<const bf16x8*>(                   \
                    &KT[1 - (P_)][(kg * 16 + col) * 64 +                        \
                                  (((ks * 4 + quad) ^ c7) << 3)]);              \
                for (int qh = 0; qh < 2; ++qh)                                  \
                    sc[1 - (P_)][kg][qh] =                                      \
                        mfma16(ak, aq[qh][ks], sc[1 - (P_)][kg][qh]);           \
            }                                                                   \
        bf16x8 bp[2][2];                                                        \
        for (int qh = 0; qh < 2; ++qh)                                          \
            for (int ks = 0; ks < 2; ++ks)                                      \
                bp[qh][ks] = *reinterpret_cast<const bf16x8*>(                  \
                    &TBw[(qh * 16 + col) * 32 + (((ks * 4 + quad) ^ c7) << 2)]);\
        for (int ks = 0; ks < 2; ++ks) {                                        \
            for (int dt = 0; dt < 4; ++dt) {                                    \
                bf16x8 av = *reinterpret_cast<const bf16x8*>(                   \
                    &VB[(P_)][(dt * 16 + col) * 64 +                            \
                              (((ks * 4 + quad) ^ c7) << 3)]);                  \
                for (int qh = 0; qh < 2; ++qh)                                  \
                    o[dt][qh] = mfma16(av, bp[qh][ks], o[dt][qh]);              \
            }                                                                   \
            accl[0] = mfma16(ones, bp[0][ks], accl[0]);                         \
            accl[1] = mfma16(ones, bp[1][ks], accl[1]);                         \
        }                                                                       \
        __syncthreads();                                                        \
    }

    FLASH_BODY(0, 0)
    for (int kth = 0; kth < 31; ++kth) {
        FLASH_BODY(2 * kth + 1, 1)
        FLASH_BODY(2 * kth + 2, 0)
    }
    {
        for (int kg = 0; kg < 4; ++kg)
            for (int qh = 0; qh < 2; ++qh) {
                f32x4 v = sc[1][kg][qh];
                uint2 u;
                u.x = pkbf(__builtin_amdgcn_exp2f(v[0]), __builtin_amdgcn_exp2f(v[1]));
                u.y = pkbf(__builtin_amdgcn_exp2f(v[2]), __builtin_amdgcn_exp2f(v[3]));
                TBw2[(qh * 16 + col) * 16 + (((kg * 2 + (quad >> 1)) ^ c7) << 1) + (quad & 1)] = u;
            }
        bf16x8 bp[2][2];
        for (int qh = 0; qh < 2; ++qh)
            for (int ks = 0; ks < 2; ++ks)
                bp[qh][ks] = *reinterpret_cast<const bf16x8*>(
                    &TBw[(qh * 16 + col) * 32 + (((ks * 4 + quad) ^ c7) << 2)]);
        for (int ks = 0; ks < 2; ++ks) {
            for (int dt = 0; dt < 4; ++dt) {
                bf16x8 av = *reinterpret_cast<const bf16x8*>(
                    &VB[1][(dt * 16 + col) * 64 + (((ks * 4 + quad) ^ c7) << 3)]);
                for (int qh = 0; qh < 2; ++qh)
                    o[dt][qh] = mfma16(av, bp[qh][ks], o[dt][qh]);
            }
            accl[0] = mfma16(ones, bp[0][ks], accl[0]);
            accl[1] = mfma16(ones, bp[1][ks], accl[1]);
        }
    }
#undef FLASH_BODY

    for (int qh = 0; qh < 2; ++qh) {
        float inv = 1.0f / accl[qh][0];
        int s = q0 + qh * 16 + col;
        __hip_bfloat16* dst = attnb + ((size_t)b * 4096 + s) * 512 + h * 64 + quad * 4;
        for (int dt = 0; dt < 4; ++dt) {
            uint2 u;
            u.x = pkbf(o[dt][qh][0] * inv, o[dt][qh][1] * inv);
            u.y = pkbf(o[dt][qh][2] * inv, o[dt][qh][3] * inv);
            *reinterpret_cast<uint2*>(dst + dt * 16) = u;
        }
    }
}

// ---------------------------------------------------------------- launch
extern "C" void kernel_launch(void* const* d_in, const int* in_sizes, int n_in,
                              void* d_out, int out_size, void* d_ws, size_t ws_size,
                              hipStream_t stream) {
    const float* X  = (const float*)d_in[0];
    const float* Wq = (const float*)d_in[1];
    const float* bq = (const float*)d_in[2];
    const float* Wk = (const float*)d_in[3];
    const float* bk = (const float*)d_in[4];
    const float* Wv = (const float*)d_in[5];
    const float* bv = (const float*)d_in[6];
    const float* Wo = (const float*)d_in[7];
    const float* bo = (const float*)d_in[8];
    float* out = (float*)d_out;

    char* ws = (char*)d_ws;
    __hip_bfloat16* Xb  = (__hip_bfloat16*)(ws);
    __hip_bfloat16* Wqt = (__hip_bfloat16*)(ws + ((size_t)8 << 20));
    __hip_bfloat16* Wkt = Wqt + 512 * 512;
    __hip_bfloat16* Wvt = Wkt + 512 * 512;
    __hip_bfloat16* Wot = Wvt + 512 * 512;
    __hip_bfloat16* Qb  = (__hip_bfloat16*)(ws + ((size_t)10 << 20));
    __hip_bfloat16* Kb  = (__hip_bfloat16*)(ws + ((size_t)18 << 20));
    __hip_bfloat16* Vtb = (__hip_bfloat16*)(ws + ((size_t)26 << 20));
    __hip_bfloat16* Atb = (__hip_bfloat16*)(ws + ((size_t)34 << 20));

    cvt_all<<<5120, 256, 0, stream>>>(X, Xb, Wq, Wk, Wv, Wo, Wqt, Wkt, Wvt, Wot);

    const float qs = 0.125f * 1.4426950408889634f;  // (1/sqrt(64)) * log2(e)
    gemm_qkv<<<dim3(12, 64), 256, 0, stream>>>(Xb, Wqt, bq, bk, bv, Qb, Kb, Vtb, qs);
    flash<<<dim3(32, 16), 256, 0, stream>>>(Qb, Kb, Vtb, Atb);
    gemm_out<<<dim3(8, 64), 256, 0, stream>>>(Atb, Wot, bo, out);
}